// Round 1
// baseline (15223.300 us; speedup 1.0000x reference)
//
#include <hip/hip_runtime.h>
#include <math.h>

#define TPB 256

// Monotonic float <-> uint order mapping for atomicMax on floats.
__device__ __forceinline__ unsigned ordf(float f) {
  unsigned u = __float_as_uint(f);
  return (u & 0x80000000u) ? ~u : (u | 0x80000000u);
}
__device__ __forceinline__ float unordf(unsigned u) {
  return (u & 0x80000000u) ? __uint_as_float(u & 0x7fffffffu) : __uint_as_float(~u);
}

__device__ __forceinline__ float leaky02(float x) { return x > 0.f ? x : 0.2f * x; }
__device__ __forceinline__ float eluf(float x) { return x > 0.f ? x : (expf(x) - 1.f); }

// h = x @ W  (no bias; bias is added post-aggregation per reference),
// alpha_src/alpha_dst per node, and init agg=0, mord=ord(-inf), s=0.
template<int IN, int OUT, int H>
__global__ void transform_kernel(const float* __restrict__ x, const float* __restrict__ W,
                                 const float* __restrict__ a_src, const float* __restrict__ a_dst,
                                 float* __restrict__ h, float* __restrict__ asrc,
                                 float* __restrict__ adst, float* __restrict__ agg,
                                 unsigned* __restrict__ mord, float* __restrict__ s, int n) {
  __shared__ float sW[IN * OUT];
  __shared__ float sa[2 * OUT];
  for (int i = threadIdx.x; i < IN * OUT; i += blockDim.x) sW[i] = W[i];
  if (threadIdx.x < OUT) {
    sa[threadIdx.x] = a_src[threadIdx.x];
    sa[OUT + threadIdx.x] = a_dst[threadIdx.x];
  }
  __syncthreads();
  int i = blockIdx.x * blockDim.x + threadIdx.x;
  if (i >= n) return;
  float xv[IN];
#pragma unroll
  for (int k = 0; k < IN; k++) xv[k] = x[(size_t)i * IN + k];
  float hv[OUT];
#pragma unroll
  for (int j = 0; j < OUT; j++) {
    float acc = 0.f;
#pragma unroll
    for (int k = 0; k < IN; k++) acc += xv[k] * sW[k * OUT + j];
    hv[j] = acc;
    h[(size_t)i * OUT + j] = acc;
    agg[(size_t)i * OUT + j] = 0.f;
  }
#pragma unroll
  for (int hh = 0; hh < H; hh++) {
    float as = 0.f, ad = 0.f;
#pragma unroll
    for (int c = 0; c < 16; c++) {
      as += hv[hh * 16 + c] * sa[hh * 16 + c];
      ad += hv[hh * 16 + c] * sa[OUT + hh * 16 + c];
    }
    asrc[i * H + hh] = as;
    adst[i * H + hh] = ad;
    mord[i * H + hh] = 0x007FFFFFu;  // ordf(-INFINITY)
    s[i * H + hh] = 0.f;
  }
}

template<int H>
__global__ void edge_max_kernel(const int* __restrict__ src, const int* __restrict__ dst,
                                int E, int n,
                                const float* __restrict__ asrc, const float* __restrict__ adst,
                                unsigned* __restrict__ mord) {
  int idx = blockIdx.x * blockDim.x + threadIdx.x;
  if (idx >= E + n) return;
  int ss, dd;
  if (idx < E) { ss = src[idx]; dd = dst[idx]; }
  else         { ss = dd = idx - E; }
#pragma unroll
  for (int hh = 0; hh < H; hh++) {
    float e = leaky02(asrc[ss * H + hh] + adst[dd * H + hh]);
    atomicMax(&mord[dd * H + hh], ordf(e));
  }
}

template<int H>
__global__ void edge_expsum_kernel(const int* __restrict__ src, const int* __restrict__ dst,
                                   int E, int n,
                                   const float* __restrict__ asrc, const float* __restrict__ adst,
                                   const unsigned* __restrict__ mord, float* __restrict__ s) {
  int idx = blockIdx.x * blockDim.x + threadIdx.x;
  if (idx >= E + n) return;
  int ss, dd;
  if (idx < E) { ss = src[idx]; dd = dst[idx]; }
  else         { ss = dd = idx - E; }
#pragma unroll
  for (int hh = 0; hh < H; hh++) {
    float e = leaky02(asrc[ss * H + hh] + adst[dd * H + hh]);
    float m = unordf(mord[dd * H + hh]);
    atomicAdd(&s[dd * H + hh], expf(e - m));
  }
}

template<int H>
__global__ void edge_agg_kernel(const int* __restrict__ src, const int* __restrict__ dst,
                                int E, int n,
                                const float* __restrict__ asrc, const float* __restrict__ adst,
                                const unsigned* __restrict__ mord, const float* __restrict__ s,
                                const float* __restrict__ h, float* __restrict__ agg) {
  int idx = blockIdx.x * blockDim.x + threadIdx.x;
  if (idx >= E + n) return;
  int ss, dd;
  if (idx < E) { ss = src[idx]; dd = dst[idx]; }
  else         { ss = dd = idx - E; }
#pragma unroll
  for (int hh = 0; hh < H; hh++) {
    float e = leaky02(asrc[ss * H + hh] + adst[dd * H + hh]);
    float m = unordf(mord[dd * H + hh]);
    float alpha = expf(e - m) / (s[dd * H + hh] + 1e-16f);
    const float* hs = h + ((size_t)ss * H + hh) * 16;
    float* ag = agg + ((size_t)dd * H + hh) * 16;
#pragma unroll
    for (int c = 0; c < 16; c++) atomicAdd(&ag[c], hs[c] * alpha);
  }
}

template<int OUT>
__global__ void finalize_kernel(const float* __restrict__ agg, const float* __restrict__ b,
                                float* __restrict__ out, int n) {
  int i = blockIdx.x * blockDim.x + threadIdx.x;
  if (i >= n * OUT) return;
  float v = agg[i] + b[i & (OUT - 1)];
  out[i] = eluf(v);
}

// Layer 3 epilogue: elu -> embeddings (d_out[n..n+16n)), sigmoid(emb@Wout+bout) -> d_out[0..n)
__global__ void finalize3_kernel(const float* __restrict__ agg, const float* __restrict__ b3,
                                 const float* __restrict__ Wout, const float* __restrict__ bout,
                                 float* __restrict__ out, int n) {
  int i = blockIdx.x * blockDim.x + threadIdx.x;
  if (i >= n) return;
  float z = bout[0];
#pragma unroll
  for (int c = 0; c < 16; c++) {
    float v = eluf(agg[(size_t)i * 16 + c] + b3[c]);
    out[(size_t)n + (size_t)i * 16 + c] = v;
    z += v * Wout[c];
  }
  out[i] = 1.f / (1.f + expf(-z));
}

extern "C" void kernel_launch(void* const* d_in, const int* in_sizes, int n_in,
                              void* d_out, int out_size, void* d_ws, size_t ws_size,
                              hipStream_t stream) {
  const float* x    = (const float*)d_in[0];
  const int*   ei   = (const int*)d_in[1];
  const float* W1   = (const float*)d_in[2];
  const float* as1  = (const float*)d_in[3];
  const float* ad1  = (const float*)d_in[4];
  const float* b1   = (const float*)d_in[5];
  const float* W2   = (const float*)d_in[6];
  const float* as2  = (const float*)d_in[7];
  const float* ad2  = (const float*)d_in[8];
  const float* b2   = (const float*)d_in[9];
  const float* W3   = (const float*)d_in[10];
  const float* as3  = (const float*)d_in[11];
  const float* ad3  = (const float*)d_in[12];
  const float* b3   = (const float*)d_in[13];
  const float* Wout = (const float*)d_in[14];
  const float* bout = (const float*)d_in[15];
  float* out = (float*)d_out;

  const int n = in_sizes[0] / 3;
  const int E = in_sizes[1] / 2;
  const int Etot = E + n;
  const int* src = ei;
  const int* dst = ei + E;

  float* ws = (float*)d_ws;
  float* bufH = ws;                              // n*32
  float* bufX = bufH + (size_t)n * 32;           // n*32
  float* agg  = bufX + (size_t)n * 32;           // n*32
  float* asrc = agg + (size_t)n * 32;            // n*2
  float* adst = asrc + (size_t)n * 2;            // n*2
  unsigned* mord = (unsigned*)(adst + (size_t)n * 2);  // n*2
  float* sbuf = (float*)(mord + (size_t)n * 2);  // n*2

  const int nbN  = (n + TPB - 1) / TPB;
  const int nbE  = (Etot + TPB - 1) / TPB;
  const int nb32 = (n * 32 + TPB - 1) / TPB;

  // ---- layer 1: in=3, out=32, H=2 ----
  transform_kernel<3, 32, 2><<<nbN, TPB, 0, stream>>>(x, W1, as1, ad1, bufH, asrc, adst, agg, mord, sbuf, n);
  edge_max_kernel<2><<<nbE, TPB, 0, stream>>>(src, dst, E, n, asrc, adst, mord);
  edge_expsum_kernel<2><<<nbE, TPB, 0, stream>>>(src, dst, E, n, asrc, adst, mord, sbuf);
  edge_agg_kernel<2><<<nbE, TPB, 0, stream>>>(src, dst, E, n, asrc, adst, mord, sbuf, bufH, agg);
  finalize_kernel<32><<<nb32, TPB, 0, stream>>>(agg, b1, bufX, n);

  // ---- layer 2: in=32, out=32, H=2 ----
  transform_kernel<32, 32, 2><<<nbN, TPB, 0, stream>>>(bufX, W2, as2, ad2, bufH, asrc, adst, agg, mord, sbuf, n);
  edge_max_kernel<2><<<nbE, TPB, 0, stream>>>(src, dst, E, n, asrc, adst, mord);
  edge_expsum_kernel<2><<<nbE, TPB, 0, stream>>>(src, dst, E, n, asrc, adst, mord, sbuf);
  edge_agg_kernel<2><<<nbE, TPB, 0, stream>>>(src, dst, E, n, asrc, adst, mord, sbuf, bufH, agg);
  finalize_kernel<32><<<nb32, TPB, 0, stream>>>(agg, b2, bufX, n);

  // ---- layer 3: in=32, out=16, H=1 ----
  transform_kernel<32, 16, 1><<<nbN, TPB, 0, stream>>>(bufX, W3, as3, ad3, bufH, asrc, adst, agg, mord, sbuf, n);
  edge_max_kernel<1><<<nbE, TPB, 0, stream>>>(src, dst, E, n, asrc, adst, mord);
  edge_expsum_kernel<1><<<nbE, TPB, 0, stream>>>(src, dst, E, n, asrc, adst, mord, sbuf);
  edge_agg_kernel<1><<<nbE, TPB, 0, stream>>>(src, dst, E, n, asrc, adst, mord, sbuf, bufH, agg);
  finalize3_kernel<<<nbN, TPB, 0, stream>>>(agg, b3, Wout, bout, out, n);
}

// Round 4
// 884.577 us; speedup vs baseline: 17.2097x; 17.2097x over previous
//
#include <hip/hip_runtime.h>
#include <math.h>

#define TPB 256

__device__ __forceinline__ float leaky02(float x) { return x > 0.f ? x : 0.2f * x; }
__device__ __forceinline__ float eluf(float x) { return x > 0.f ? x : (expf(x) - 1.f); }

// ====================== CSR build (counting sort by dst) ======================

__global__ void zero_kernel(int* __restrict__ p, int n) {
  int i = blockIdx.x * blockDim.x + threadIdx.x;
  if (i < n) p[i] = 0;
}

__global__ void hist_kernel(const int* __restrict__ dst, int E, int n, int* __restrict__ deg) {
  int idx = blockIdx.x * blockDim.x + threadIdx.x;
  if (idx >= E + n) return;
  int dd = (idx < E) ? dst[idx] : (idx - E);
  atomicAdd(&deg[dd], 1);
}

// per-block reduce of deg -> bsum[block]
__global__ void scanA_kernel(const int* __restrict__ deg, int n, int* __restrict__ bsum) {
  __shared__ int sm[TPB];
  int i = blockIdx.x * TPB + threadIdx.x;
  sm[threadIdx.x] = (i < n) ? deg[i] : 0;
  __syncthreads();
  for (int off = TPB / 2; off >= 1; off >>= 1) {
    if (threadIdx.x < off) sm[threadIdx.x] += sm[threadIdx.x + off];
    __syncthreads();
  }
  if (threadIdx.x == 0) bsum[blockIdx.x] = sm[0];
}

// single block of 512: exclusive scan of bsum in place (nb <= 512)
__global__ void scanB_kernel(int* __restrict__ bsum, int nb) {
  __shared__ int sm[512];
  int t = threadIdx.x;
  int v = (t < nb) ? bsum[t] : 0;
  sm[t] = v;
  __syncthreads();
  for (int off = 1; off < 512; off <<= 1) {
    int a = (t >= off) ? sm[t - off] : 0;
    __syncthreads();
    sm[t] += a;
    __syncthreads();
  }
  if (t < nb) bsum[t] = sm[t] - v;  // exclusive
}

// per-block exclusive scan + block offset -> rowptr, cursor
__global__ void scanC_kernel(const int* __restrict__ deg, const int* __restrict__ boff, int n,
                             int* __restrict__ rowptr, int* __restrict__ cursor) {
  __shared__ int sm[TPB];
  int t = threadIdx.x;
  int i = blockIdx.x * TPB + t;
  int v = (i < n) ? deg[i] : 0;
  sm[t] = v;
  __syncthreads();
  for (int off = 1; off < TPB; off <<= 1) {
    int a = (t >= off) ? sm[t - off] : 0;
    __syncthreads();
    sm[t] += a;
    __syncthreads();
  }
  if (i < n) {
    int ex = boff[blockIdx.x] + sm[t] - v;
    rowptr[i] = ex;
    cursor[i] = ex;
  }
}

__global__ void scatter_kernel(const int* __restrict__ src, const int* __restrict__ dst,
                               int E, int n, int* __restrict__ cursor, int* __restrict__ csr_src) {
  int idx = blockIdx.x * blockDim.x + threadIdx.x;
  if (idx >= E + n) return;
  int ss, dd;
  if (idx < E) { ss = src[idx]; dd = dst[idx]; }
  else         { ss = dd = idx - E; }
  int pos = atomicAdd(&cursor[dd], 1);
  csr_src[pos] = ss;
}

// ====================== node transform (h = x@W, attn logits) ======================

template<int IN, int OUT, int H>
__global__ void transform_kernel(const float* __restrict__ x, const float* __restrict__ W,
                                 const float* __restrict__ a_src, const float* __restrict__ a_dst,
                                 float* __restrict__ h, float* __restrict__ asrc,
                                 float* __restrict__ adst, int n) {
  __shared__ float sW[IN * OUT];
  __shared__ float sa[2 * OUT];
  for (int i = threadIdx.x; i < IN * OUT; i += blockDim.x) sW[i] = W[i];
  if (threadIdx.x < OUT) {
    sa[threadIdx.x] = a_src[threadIdx.x];
    sa[OUT + threadIdx.x] = a_dst[threadIdx.x];
  }
  __syncthreads();
  int i = blockIdx.x * blockDim.x + threadIdx.x;
  if (i >= n) return;
  float xv[IN];
#pragma unroll
  for (int k = 0; k < IN; k++) xv[k] = x[(size_t)i * IN + k];
  float hv[OUT];
#pragma unroll
  for (int j = 0; j < OUT; j++) {
    float acc = 0.f;
#pragma unroll
    for (int k = 0; k < IN; k++) acc += xv[k] * sW[k * OUT + j];
    hv[j] = acc;
    h[(size_t)i * OUT + j] = acc;
  }
#pragma unroll
  for (int hh = 0; hh < H; hh++) {
    float as = 0.f, ad = 0.f;
#pragma unroll
    for (int c = 0; c < 16; c++) {
      as += hv[hh * 16 + c] * sa[hh * 16 + c];
      ad += hv[hh * 16 + c] * sa[OUT + hh * 16 + c];
    }
    asrc[i * H + hh] = as;
    adst[i * H + hh] = ad;
  }
}

// ====================== per-node GAT aggregation (1 wave / dst node) ======================
// LDS-staged, stride-indexed: phase 1 max, phase 2 exp-sum -> per-edge alpha,
// phase 3 stage (sidx, alpha) in LDS and gather h with per-lane strided loop.

// H=2, C=16 (layers 1 & 2). Writes elu(agg + bias) -> outb[n*32].
__global__ __launch_bounds__(256) void node_gat12(
    const int* __restrict__ rowptr, const int* __restrict__ deg,
    const int* __restrict__ csr_src,
    const float* __restrict__ asrc,  // [n*2]
    const float* __restrict__ adst,  // [n*2]
    const float* __restrict__ hfeat, // [n*32]
    const float* __restrict__ bias,  // [32]
    float* __restrict__ outb,        // [n*32]
    int n) {
  __shared__ int   s_sidx[4][64];
  __shared__ float s_a0[4][64];
  __shared__ float s_a1[4][64];
  int wid = threadIdx.x >> 6;
  int lane = threadIdx.x & 63;
  int i = (blockIdx.x * blockDim.x + threadIdx.x) >> 6;
  if (i >= n) return;
  int start = rowptr[i];
  int d = deg[i];
  float ad0 = adst[i * 2 + 0];
  float ad1 = adst[i * 2 + 1];

  // ---- phase 1: max of e per head ----
  float m0 = -3.4e38f, m1 = -3.4e38f;
  for (int k = lane; k < d; k += 64) {
    int sidx = csr_src[start + k];
    float2 av = ((const float2*)asrc)[sidx];
    m0 = fmaxf(m0, leaky02(av.x + ad0));
    m1 = fmaxf(m1, leaky02(av.y + ad1));
  }
#pragma unroll
  for (int off = 32; off >= 1; off >>= 1) {
    m0 = fmaxf(m0, __shfl_xor(m0, off));
    m1 = fmaxf(m1, __shfl_xor(m1, off));
  }

  // ---- phase 2: exp-sum per head -> inv ----
  float sl0 = 0.f, sl1 = 0.f;
  for (int k = lane; k < d; k += 64) {
    int sidx = csr_src[start + k];
    float2 av = ((const float2*)asrc)[sidx];
    sl0 += expf(leaky02(av.x + ad0) - m0);
    sl1 += expf(leaky02(av.y + ad1) - m1);
  }
#pragma unroll
  for (int off = 32; off >= 1; off >>= 1) {
    sl0 += __shfl_xor(sl0, off);
    sl1 += __shfl_xor(sl1, off);
  }
  float inv0 = 1.f / (sl0 + 1e-16f);
  float inv1 = 1.f / (sl1 + 1e-16f);

  // ---- phase 3: per-edge alpha staged in LDS; strided gather-accumulate ----
  int head = (lane >> 4) & 1;   // head of my channel
  int c = lane & 31;            // my channel (0..31)
  int half = lane >> 5;         // which parity of edges I accumulate
  float acc = 0.f;
  for (int base = 0; base < d; base += 64) {
    int k = base + lane;
    int sidx = 0;
    float a0 = 0.f, a1 = 0.f;
    if (k < d) {
      sidx = csr_src[start + k];
      float2 av = ((const float2*)asrc)[sidx];
      a0 = expf(leaky02(av.x + ad0) - m0) * inv0;
      a1 = expf(leaky02(av.y + ad1) - m1) * inv1;
    }
    s_sidx[wid][lane] = sidx;
    s_a0[wid][lane] = a0;
    s_a1[wid][lane] = a1;
    // same-wave LDS write->read: DS pipe processes a wave's ops in order.
    int cnt = min(64, d - base);
    for (int jj = half; jj < cnt; jj += 2) {
      int sb = s_sidx[wid][jj];
      float wb = head ? s_a1[wid][jj] : s_a0[wid][jj];
      acc += wb * hfeat[(size_t)sb * 32 + c];
    }
  }
  // combine the two edge-parity halves
  acc += __shfl_xor(acc, 32);
  if (lane < 32) {
    outb[(size_t)i * 32 + c] = eluf(acc + bias[c]);
  }
}

// H=1, C=16 (layer 3) + fused output head.
__global__ __launch_bounds__(256) void node_gat3(
    const int* __restrict__ rowptr, const int* __restrict__ deg,
    const int* __restrict__ csr_src,
    const float* __restrict__ asrc,  // [n]
    const float* __restrict__ adst,  // [n]
    const float* __restrict__ hfeat, // [n*16]
    const float* __restrict__ b3,    // [16]
    const float* __restrict__ Wout,  // [16]
    const float* __restrict__ bout,  // [1]
    float* __restrict__ out,         // [n] sigmoid ++ [n*16] embeddings
    int n) {
  __shared__ int   s_sidx[4][64];
  __shared__ float s_a0[4][64];
  int wid = threadIdx.x >> 6;
  int lane = threadIdx.x & 63;
  int i = (blockIdx.x * blockDim.x + threadIdx.x) >> 6;
  if (i >= n) return;
  int start = rowptr[i];
  int d = deg[i];
  float ad0 = adst[i];

  // ---- phase 1: max ----
  float m0 = -3.4e38f;
  for (int k = lane; k < d; k += 64) {
    int sidx = csr_src[start + k];
    m0 = fmaxf(m0, leaky02(asrc[sidx] + ad0));
  }
#pragma unroll
  for (int off = 32; off >= 1; off >>= 1) m0 = fmaxf(m0, __shfl_xor(m0, off));

  // ---- phase 2: exp-sum -> inv ----
  float sl0 = 0.f;
  for (int k = lane; k < d; k += 64) {
    int sidx = csr_src[start + k];
    sl0 += expf(leaky02(asrc[sidx] + ad0) - m0);
  }
#pragma unroll
  for (int off = 32; off >= 1; off >>= 1) sl0 += __shfl_xor(sl0, off);
  float inv = 1.f / (sl0 + 1e-16f);

  // ---- phase 3: staged alpha + strided gather ----
  int c = lane & 15;
  int quarter = lane >> 4;  // 0..3
  float acc = 0.f;
  for (int base = 0; base < d; base += 64) {
    int k = base + lane;
    int sidx = 0;
    float a0 = 0.f;
    if (k < d) {
      sidx = csr_src[start + k];
      a0 = expf(leaky02(asrc[sidx] + ad0) - m0) * inv;
    }
    s_sidx[wid][lane] = sidx;
    s_a0[wid][lane] = a0;
    int cnt = min(64, d - base);
    for (int jj = quarter; jj < cnt; jj += 4) {
      int sb = s_sidx[wid][jj];
      acc += s_a0[wid][jj] * hfeat[(size_t)sb * 16 + c];
    }
  }
  acc += __shfl_xor(acc, 32);
  acc += __shfl_xor(acc, 16);

  float v = 0.f, z = 0.f;
  if (lane < 16) {
    v = eluf(acc + b3[c]);
    out[(size_t)n + (size_t)i * 16 + c] = v;
    z = v * Wout[c];
  }
#pragma unroll
  for (int off = 8; off >= 1; off >>= 1) z += __shfl_xor(z, off);
  if (lane == 0) out[i] = 1.f / (1.f + expf(-(z + bout[0])));
}

// ====================== launch ======================

extern "C" void kernel_launch(void* const* d_in, const int* in_sizes, int n_in,
                              void* d_out, int out_size, void* d_ws, size_t ws_size,
                              hipStream_t stream) {
  const float* x    = (const float*)d_in[0];
  const int*   ei   = (const int*)d_in[1];
  const float* W1   = (const float*)d_in[2];
  const float* as1  = (const float*)d_in[3];
  const float* ad1  = (const float*)d_in[4];
  const float* b1   = (const float*)d_in[5];
  const float* W2   = (const float*)d_in[6];
  const float* as2  = (const float*)d_in[7];
  const float* ad2  = (const float*)d_in[8];
  const float* b2   = (const float*)d_in[9];
  const float* W3   = (const float*)d_in[10];
  const float* as3  = (const float*)d_in[11];
  const float* ad3  = (const float*)d_in[12];
  const float* b3   = (const float*)d_in[13];
  const float* Wout = (const float*)d_in[14];
  const float* bout = (const float*)d_in[15];
  float* out = (float*)d_out;

  const int n = in_sizes[0] / 3;
  const int E = in_sizes[1] / 2;
  const int Etot = E + n;
  const int* src = ei;
  const int* dst = ei + E;

  // workspace layout
  float* ws = (float*)d_ws;
  float* bufH = ws;                               // n*32
  float* bufX = bufH + (size_t)n * 32;            // n*32
  float* asrc = bufX + (size_t)n * 32;            // n*2
  float* adst = asrc + (size_t)n * 2;             // n*2
  int* rowptr  = (int*)(adst + (size_t)n * 2);    // n
  int* deg     = rowptr + n;                      // n
  int* cursor  = deg + n;                         // n
  int* bsum    = cursor + n;                      // 512
  int* csr_src = bsum + 512;                      // E+n

  const int nbN = (n + TPB - 1) / TPB;
  const int nbE = (Etot + TPB - 1) / TPB;
  const int nbW = (n + 3) / 4;  // 1 wave per node, 4 waves/block

  // ---- CSR build (once, reused by all 3 layers) ----
  zero_kernel<<<nbN, TPB, 0, stream>>>(deg, n);
  hist_kernel<<<nbE, TPB, 0, stream>>>(dst, E, n, deg);
  scanA_kernel<<<nbN, TPB, 0, stream>>>(deg, n, bsum);
  scanB_kernel<<<1, 512, 0, stream>>>(bsum, nbN);
  scanC_kernel<<<nbN, TPB, 0, stream>>>(deg, bsum, n, rowptr, cursor);
  scatter_kernel<<<nbE, TPB, 0, stream>>>(src, dst, E, n, cursor, csr_src);

  // ---- layer 1: in=3, out=32, H=2 ----
  transform_kernel<3, 32, 2><<<nbN, TPB, 0, stream>>>(x, W1, as1, ad1, bufH, asrc, adst, n);
  node_gat12<<<nbW, TPB, 0, stream>>>(rowptr, deg, csr_src, asrc, adst, bufH, b1, bufX, n);

  // ---- layer 2: in=32, out=32, H=2 ----
  transform_kernel<32, 32, 2><<<nbN, TPB, 0, stream>>>(bufX, W2, as2, ad2, bufH, asrc, adst, n);
  node_gat12<<<nbW, TPB, 0, stream>>>(rowptr, deg, csr_src, asrc, adst, bufH, b2, bufX, n);

  // ---- layer 3: in=32, out=16, H=1 ----
  transform_kernel<32, 16, 1><<<nbN, TPB, 0, stream>>>(bufX, W3, as3, ad3, bufH, asrc, adst, n);
  node_gat3<<<nbW, TPB, 0, stream>>>(rowptr, deg, csr_src, asrc, adst, bufH, b3, Wout, bout, out, n);
}